// Round 5
// baseline (167.310 us; speedup 1.0000x reference)
//
#include <hip/hip_runtime.h>

#define NB 16
#define SS 2048
#define DD 64

typedef __attribute__((ext_vector_type(8))) short short8;
typedef __attribute__((ext_vector_type(4))) float f32x4;

// SCALE * log2(e), folded so softmax exp is one v_mul + one v_exp
#define SCL2E 0.18033688011112042f

// round-to-nearest-even f32 -> bf16 (as raw short)
__device__ __forceinline__ short f2bf(float f) {
  union { float f; unsigned u; } v; v.f = f;
  unsigned r = (v.u + 0x7fffu + ((v.u >> 16) & 1u)) >> 16;
  return (short)r;
}

// packed RNE f32x2 -> bf16x2 (no builtin on gfx950; guide T12)
__device__ __forceinline__ unsigned cvtpk_bf16(float lo, float hi) {
  unsigned r;
  asm("v_cvt_pk_bf16_f32 %0, %1, %2" : "=v"(r) : "v"(lo), "v"(hi));
  return r;
}

__device__ __forceinline__ short8 load_a_frag_f32(const float* p) {
  float4 u = *(const float4*)p;
  float4 w = *(const float4*)(p + 4);
  short8 r;
  r[0] = f2bf(u.x); r[1] = f2bf(u.y); r[2] = f2bf(u.z); r[3] = f2bf(u.w);
  r[4] = f2bf(w.x); r[5] = f2bf(w.y); r[6] = f2bf(w.z); r[7] = f2bf(w.w);
  return r;
}

// ---------------------------------------------------------------------------
// QKV projection: 768 threads (12 waves), 512 blocks, 64 rows/block.
// Wave w owns matrix m = w>>2 and rows (w&3)*16. Q,K row-major bf16.
// V is written TILED: vtile[b][kt][d][64 keys] (8 KB contiguous per 64-key
// tile) -- one block produces exactly one tile, stores fully coalesced.
// This kills the old stride-4096 vT row layout (L2 channel camping suspect).
// ---------------------------------------------------------------------------
__global__ __launch_bounds__(768) void proj_kernel(
    const float* __restrict__ x,
    const float* __restrict__ Wq, const float* __restrict__ bq,
    const float* __restrict__ Wk, const float* __restrict__ bk,
    const float* __restrict__ Wv, const float* __restrict__ bv,
    ushort* __restrict__ qo, ushort* __restrict__ ko, ushort* __restrict__ vt)
{
  __shared__ __align__(16) ushort Wt[3][64][72];   // W^T[n][k], bf16
  __shared__ __align__(16) ushort Vs[64][68];
  const int t = threadIdx.x;
  // stage all three W^T: 12288 elems over 768 threads (4 elems x 4 iters)
#pragma unroll
  for (int i = 0; i < 4; ++i) {
    int idx = i * 3072 + t * 4;
    int m = idx >> 12, rem = idx & 4095;
    int kk = rem >> 6, n0 = rem & 63;
    const float* src = (m == 0 ? Wq : (m == 1 ? Wk : Wv));
    float4 w4 = *(const float4*)(src + rem);
    Wt[m][n0 + 0][kk] = (ushort)f2bf(w4.x);
    Wt[m][n0 + 1][kk] = (ushort)f2bf(w4.y);
    Wt[m][n0 + 2][kk] = (ushort)f2bf(w4.z);
    Wt[m][n0 + 3][kk] = (ushort)f2bf(w4.w);
  }
  __syncthreads();

  const int lane = t & 63, w = t >> 6;   // w in 0..11
  const int l15 = lane & 15, quad = lane >> 4;
  const int mm = w >> 2, rr = w & 3;     // matrix, row-quarter
  const int g = blockIdx.x * 64 + rr * 16 + l15;

  // B-frags: x row g (waves with same rr share rows; L1 hits)
  short8 b0 = load_a_frag_f32(x + (size_t)g * 64 + quad * 8);
  short8 b1 = load_a_frag_f32(x + (size_t)g * 64 + 32 + quad * 8);

  const float* bp = (mm == 0 ? bq : (mm == 1 ? bk : bv));
  ushort* outp = (mm == 0 ? qo : ko);

#pragma unroll
  for (int nt = 0; nt < 4; ++nt) {
    short8 a0 = *(const short8*)&Wt[mm][nt * 16 + l15][quad * 8];
    short8 a1 = *(const short8*)&Wt[mm][nt * 16 + l15][32 + quad * 8];
    f32x4 acc = {0.f, 0.f, 0.f, 0.f};
    acc = __builtin_amdgcn_mfma_f32_16x16x32_bf16(a0, b0, acc, 0, 0, 0);
    acc = __builtin_amdgcn_mfma_f32_16x16x32_bf16(a1, b1, acc, 0, 0, 0);
    float4 bb = *(const float4*)(bp + nt * 16 + quad * 4);
    uint2 pk;
    pk.x = cvtpk_bf16(acc[0] + bb.x, acc[1] + bb.y);
    pk.y = cvtpk_bf16(acc[2] + bb.z, acc[3] + bb.w);
    if (mm == 2) {
      *(uint2*)&Vs[rr * 16 + l15][nt * 16 + quad * 4] = pk;
    } else {
      *(uint2*)(outp + (size_t)g * 64 + nt * 16 + quad * 4) = pk;
    }
  }
  __syncthreads();
  if (t < 256) {
    const int batch = blockIdx.x >> 5;
    const int ktile = blockIdx.x & 31;
    const int d = t >> 2, j0 = (t & 3) * 16;
    ushort tmp[16];
#pragma unroll
    for (int j = 0; j < 16; ++j) tmp[j] = Vs[j0 + j][d];
    // vtile[b][ktile][d][64]: fully coalesced (4 KB contiguous per wave)
    ushort* dst = vt + (size_t)batch * SS * DD + ktile * 4096 + d * 64 + j0;
    ((int4*)dst)[0] = ((int4*)tmp)[0];
    ((int4*)dst)[1] = ((int4*)tmp)[1];
  }
}

// ---------------------------------------------------------------------------
// In-register P redistribution (verified passing r1-r4).
// ---------------------------------------------------------------------------
__device__ __forceinline__ short8 build_pa(unsigned A0, unsigned A1,
                                           unsigned B0, unsigned B1, int quad) {
  int xA0 = __shfl_xor((int)A0, 32);
  int xA1 = __shfl_xor((int)A1, 32);
  int xB0 = __shfl_xor((int)B0, 32);
  int xB1 = __shfl_xor((int)B1, 32);
  const bool hi = quad >= 2;
  const bool odd = quad & 1;
  int Lo0 = hi ? xB0 : (int)A0;   // [A_lo | B_lo]
  int Lo1 = hi ? xB1 : (int)A1;
  int Hi0 = hi ? (int)B0 : xA0;   // [A_hi | B_hi]
  int Hi1 = hi ? (int)B1 : xA1;
  int xLo0 = __shfl_xor(Lo0, 16);
  int xLo1 = __shfl_xor(Lo1, 16);
  int xHi0 = __shfl_xor(Hi0, 16);
  int xHi1 = __shfl_xor(Hi1, 16);
  int4 wv;
  wv.x = odd ? xHi0 : Lo0;   // keys quad*8 + 0,1
  wv.y = odd ? xHi1 : Lo1;   // keys quad*8 + 2,3
  wv.z = odd ? Hi0 : xLo0;   // keys quad*8 + 4,5
  wv.w = odd ? Hi1 : xLo1;   // keys quad*8 + 6,7
  return *(short8*)&wv;
}

// exp + in-register P build + PV for one 16-query group. MASKED compile-time.
template<bool MASKED>
__device__ __forceinline__ void attn_half(
    const f32x4 (&c)[4], float& l_acc, f32x4 (&acc)[4],
    const short8 (&vf0)[4], const short8 (&vf1)[4],
    int keybase, int qabs, int quad)
{
  unsigned pk[4][2];
#pragma unroll
  for (int ct = 0; ct < 4; ++ct) {
    float pe[4];
#pragma unroll
    for (int r = 0; r < 4; ++r) {
      float p = __builtin_amdgcn_exp2f(c[ct][r] * SCL2E);
      if (MASKED && (keybase + ct * 16 + quad * 4 + r > qabs)) p = 0.f;
      pe[r] = p;
      l_acc += p;
    }
    pk[ct][0] = cvtpk_bf16(pe[0], pe[1]);
    pk[ct][1] = cvtpk_bf16(pe[2], pe[3]);
  }
  short8 pa0 = build_pa(pk[0][0], pk[0][1], pk[1][0], pk[1][1], quad);
  short8 pa1 = build_pa(pk[2][0], pk[2][1], pk[3][0], pk[3][1], quad);
  __builtin_amdgcn_s_setprio(1);
#pragma unroll
  for (int nt = 0; nt < 4; ++nt) {
    acc[nt] = __builtin_amdgcn_mfma_f32_16x16x32_bf16(pa0, vf0[nt], acc[nt], 0, 0, 0);
    acc[nt] = __builtin_amdgcn_mfma_f32_16x16x32_bf16(pa1, vf1[nt], acc[nt], 0, 0, 0);
  }
  __builtin_amdgcn_s_setprio(0);
}

// ---------------------------------------------------------------------------
// Flash causal attention v7 -- Q-SPLIT waves, barrier-free, LDS-free.
// 64 queries/block; wave w owns queries qt*64 + w*16 .. +15 and iterates over
// ALL its key tiles. All 4 waves read the SAME K/V tile per iteration -> L1
// hits for 3 of 4 reads (K-split never reused tiles within the CU).
// V is read from vtile[b][kt][d][64]: stride-128 pattern identical to K,
// tile-contiguous 8 KB -- no stride-4096 channel camping.
// Each wave finishes its own softmax and writes output directly:
// no LDS, no barriers, no combine. Waves drain independently.
// ---------------------------------------------------------------------------
__global__ __launch_bounds__(256) void attn_kernel(
    const ushort* __restrict__ qg, const ushort* __restrict__ kg,
    const ushort* __restrict__ vt, float* __restrict__ out)
{
  const int t = threadIdx.x, bid = blockIdx.x;
  const int batch = (bid & 7) * 2 + ((bid >> 3) & 1);  // 2 batches per XCD
  const int qt = 31 - (bid >> 4);                      // heavy blocks first
  const int lane = t & 63, w = t >> 6;
  const int l15 = lane & 15, quad = lane >> 4;
  const int qrow0 = qt * 64 + w * 16;                  // wave's 16 queries
  const size_t bbase = (size_t)batch * SS * DD;

  // Q fragments (B operand of swapped QK): lane l15 = query row
  const ushort* qp = qg + bbase + (size_t)(qrow0 + l15) * 64 + quad * 8;
  short8 a0 = *(const short8*)qp;
  short8 a1 = *(const short8*)(qp + 32);

  f32x4 acc[4];
  float l0 = 0.f;
#pragma unroll
  for (int nt = 0; nt < 4; ++nt) acc[nt] = (f32x4){0.f, 0.f, 0.f, 0.f};

  const int ktot = ((qrow0 + 15) >> 6) + 1;   // 64-key tiles for this wave
  // K rows l15 (+16/32/48 via imm), dims quad*8; tile step = 4096 elems
  const ushort* kpA = kg + bbase + l15 * 64 + quad * 8;
  const ushort* kpB = kpA + 2048;
  // vtile rows d = l15 (+16/32/48), keys quad*8 (+32); tile step = 4096 elems
  const ushort* vpA = vt + bbase + l15 * 64 + quad * 8;
  const ushort* vpB = vpA + 2048;
  const int qabs = qrow0 + l15;

  for (int kt = 0; kt < ktot; ++kt) {
    short8 kf0[4], kf1[4], vf0[4], vf1[4];
    // K first (QK consumes them first; counted vmcnt leaves V in flight)
    kf0[0] = *(const short8*)(kpA);        kf1[0] = *(const short8*)(kpA + 32);
    kf0[1] = *(const short8*)(kpA + 1024); kf1[1] = *(const short8*)(kpA + 1056);
    kf0[2] = *(const short8*)(kpB);        kf1[2] = *(const short8*)(kpB + 32);
    kf0[3] = *(const short8*)(kpB + 1024); kf1[3] = *(const short8*)(kpB + 1056);
    vf0[0] = *(const short8*)(vpA);        vf1[0] = *(const short8*)(vpA + 32);
    vf0[1] = *(const short8*)(vpA + 1024); vf1[1] = *(const short8*)(vpA + 1056);
    vf0[2] = *(const short8*)(vpB);        vf1[2] = *(const short8*)(vpB + 32);
    vf0[3] = *(const short8*)(vpB + 1024); vf1[3] = *(const short8*)(vpB + 1056);

    // Swapped QK: c = mfma(K, Q) -> S^T tile; lane l15 = query.
    f32x4 c[4];
    __builtin_amdgcn_s_setprio(1);
#pragma unroll
    for (int ct = 0; ct < 4; ++ct) {
      f32x4 z = {0.f, 0.f, 0.f, 0.f};
      c[ct] = __builtin_amdgcn_mfma_f32_16x16x32_bf16(kf0[ct], a0, z, 0, 0, 0);
      c[ct] = __builtin_amdgcn_mfma_f32_16x16x32_bf16(kf1[ct], a1, c[ct], 0, 0, 0);
    }
    __builtin_amdgcn_s_setprio(0);

    if (kt == ktot - 1)
      attn_half<true >(c, l0, acc, vf0, vf1, kt * 64, qabs, quad);
    else
      attn_half<false>(c, l0, acc, vf0, vf1, kt * 64, qabs, quad);

    kpA += 4096; kpB += 4096; vpA += 4096; vpB += 4096;
  }

  // l is per-lane (q = l15); sum across the 4 quads holding different keys
  l0 += __shfl_xor(l0, 16);
  l0 += __shfl_xor(l0, 32);

  // direct store: lane(l15,quad) holds out[q = qrow0+quad*4+r][d = nt*16+l15]
  float* ob = out + bbase;
#pragma unroll
  for (int r = 0; r < 4; ++r) {
    float den = __shfl(l0, quad * 4 + r);   // lane quad*4+r holds l for that q
    float iv = 1.0f / den;
    float* orow = ob + (size_t)(qrow0 + quad * 4 + r) * 64 + l15;
#pragma unroll
    for (int nt = 0; nt < 4; ++nt)
      orow[nt * 16] = acc[nt][r] * iv;
  }
}

extern "C" void kernel_launch(void* const* d_in, const int* in_sizes, int n_in,
                              void* d_out, int out_size, void* d_ws, size_t ws_size,
                              hipStream_t stream) {
  (void)in_sizes; (void)n_in; (void)out_size; (void)ws_size;
  const float* x  = (const float*)d_in[0];
  const float* Wq = (const float*)d_in[1];
  const float* bq = (const float*)d_in[2];
  const float* Wk = (const float*)d_in[3];
  const float* bk = (const float*)d_in[4];
  const float* Wv = (const float*)d_in[5];
  const float* bv = (const float*)d_in[6];
  float* out = (float*)d_out;

  ushort* qws = (ushort*)d_ws;                       // bf16 q: 4 MB
  ushort* kws = qws + (size_t)NB * SS * DD;          // bf16 k: 4 MB
  ushort* vws = kws + (size_t)NB * SS * DD;          // bf16 vtile: 4 MB

  proj_kernel<<<dim3(NB * SS / 64), dim3(768), 0, stream>>>(
      x, Wq, bq, Wk, bk, Wv, bv, qws, kws, vws);
  attn_kernel<<<dim3(NB * (SS / 64)), dim3(256), 0, stream>>>(
      qws, kws, vws, out);
}

// Round 6
// 130.335 us; speedup vs baseline: 1.2837x; 1.2837x over previous
//
#include <hip/hip_runtime.h>

#define NB 16
#define SS 2048
#define DD 64

typedef __attribute__((ext_vector_type(8))) short short8;
typedef __attribute__((ext_vector_type(4))) float f32x4;

// SCALE * log2(e), folded so softmax exp is one v_mul + one v_exp
#define SCL2E 0.18033688011112042f

// round-to-nearest-even f32 -> bf16 (as raw short)
__device__ __forceinline__ short f2bf(float f) {
  union { float f; unsigned u; } v; v.f = f;
  unsigned r = (v.u + 0x7fffu + ((v.u >> 16) & 1u)) >> 16;
  return (short)r;
}

// packed RNE f32x2 -> bf16x2 (no builtin on gfx950; guide T12)
__device__ __forceinline__ unsigned cvtpk_bf16(float lo, float hi) {
  unsigned r;
  asm("v_cvt_pk_bf16_f32 %0, %1, %2" : "=v"(r) : "v"(lo), "v"(hi));
  return r;
}

__device__ __forceinline__ short8 load_a_frag_f32(const float* p) {
  float4 u = *(const float4*)p;
  float4 w = *(const float4*)(p + 4);
  short8 r;
  r[0] = f2bf(u.x); r[1] = f2bf(u.y); r[2] = f2bf(u.z); r[3] = f2bf(u.w);
  r[4] = f2bf(w.x); r[5] = f2bf(w.y); r[6] = f2bf(w.z); r[7] = f2bf(w.w);
  return r;
}

// ---------------------------------------------------------------------------
// One-shot W transpose: Wt[m][n][k] = W[k][n] as bf16, k-contiguous (r1,
// harness-verified). 24 KB total -> L2-resident for all proj blocks.
// ---------------------------------------------------------------------------
__global__ __launch_bounds__(256) void wprep_kernel(
    const float* __restrict__ Wq, const float* __restrict__ Wk,
    const float* __restrict__ Wv, ushort* __restrict__ Wt)
{
  const float* Ws[3] = {Wq, Wk, Wv};
  const int m = blockIdx.x;
  const float* src = Ws[m];
  ushort* dst = Wt + m * 4096;
  const int t = threadIdx.x;
#pragma unroll
  for (int i = 0; i < 4; ++i) {
    int idx = i * 1024 + t * 4;
    int k = idx >> 6, n0 = idx & 63;
    float4 w4 = *(const float4*)(src + idx);
    dst[(n0 + 0) * 64 + k] = (ushort)f2bf(w4.x);
    dst[(n0 + 1) * 64 + k] = (ushort)f2bf(w4.y);
    dst[(n0 + 2) * 64 + k] = (ushort)f2bf(w4.z);
    dst[(n0 + 3) * 64 + k] = (ushort)f2bf(w4.w);
  }
}

// ---------------------------------------------------------------------------
// QKV projection v7: grid (512 rowgroups, 3 matrices), 256 thr (4 waves of
// 16 rows). No per-block W staging (global bf16 W^T, L1/L2-hit), no barrier
// for Q/K blocks. V blocks transpose via LDS + 1 barrier into
// vtile[b][kt][d][64] (read layout proven in r5).
// 6144 waves = 24/CU (3x the old wave count), ~300-cycle body each.
// ---------------------------------------------------------------------------
__global__ __launch_bounds__(256) void proj_kernel(
    const float* __restrict__ x, const ushort* __restrict__ Wt,
    const float* __restrict__ bq, const float* __restrict__ bk,
    const float* __restrict__ bv,
    ushort* __restrict__ qo, ushort* __restrict__ ko, ushort* __restrict__ vt)
{
  __shared__ __align__(16) ushort Vs[64][68];
  const int t = threadIdx.x;
  const int lane = t & 63, w = t >> 6;
  const int l15 = lane & 15, quad = lane >> 4;
  const int rowgroup = blockIdx.x, mm = blockIdx.y;
  const int g = rowgroup * 64 + w * 16 + l15;

  // B-frags: x row g
  short8 b0 = load_a_frag_f32(x + (size_t)g * 64 + quad * 8);
  short8 b1 = load_a_frag_f32(x + (size_t)g * 64 + 32 + quad * 8);

  const float* bp = (mm == 0 ? bq : (mm == 1 ? bk : bv));
  const ushort* wm = Wt + mm * 4096;
  ushort* outp = (mm == 0 ? qo : ko);

#pragma unroll
  for (int nt = 0; nt < 4; ++nt) {
    const ushort* ap = wm + (nt * 16 + l15) * 64 + quad * 8;
    short8 a0 = *(const short8*)ap;
    short8 a1 = *(const short8*)(ap + 32);
    f32x4 acc = {0.f, 0.f, 0.f, 0.f};
    acc = __builtin_amdgcn_mfma_f32_16x16x32_bf16(a0, b0, acc, 0, 0, 0);
    acc = __builtin_amdgcn_mfma_f32_16x16x32_bf16(a1, b1, acc, 0, 0, 0);
    float4 bb = *(const float4*)(bp + nt * 16 + quad * 4);
    uint2 pk;
    pk.x = cvtpk_bf16(acc[0] + bb.x, acc[1] + bb.y);
    pk.y = cvtpk_bf16(acc[2] + bb.z, acc[3] + bb.w);
    if (mm == 2) {
      *(uint2*)&Vs[w * 16 + l15][nt * 16 + quad * 4] = pk;
    } else {
      *(uint2*)(outp + (size_t)g * 64 + nt * 16 + quad * 4) = pk;
    }
  }
  if (mm == 2) {
    __syncthreads();
    const int batch = rowgroup >> 5;
    const int ktile = rowgroup & 31;
    const int d = t >> 2, j0 = (t & 3) * 16;
    ushort tmp[16];
#pragma unroll
    for (int j = 0; j < 16; ++j) tmp[j] = Vs[j0 + j][d];
    // vtile[b][ktile][d][64]: 4 KB contiguous per wave, coalesced
    ushort* dst = vt + (size_t)batch * SS * DD + ktile * 4096 + d * 64 + j0;
    ((int4*)dst)[0] = ((int4*)tmp)[0];
    ((int4*)dst)[1] = ((int4*)tmp)[1];
  }
}

// ---------------------------------------------------------------------------
// In-register P redistribution (harness-verified r1-r5).
// ---------------------------------------------------------------------------
__device__ __forceinline__ short8 build_pa(unsigned A0, unsigned A1,
                                           unsigned B0, unsigned B1, int quad) {
  int xA0 = __shfl_xor((int)A0, 32);
  int xA1 = __shfl_xor((int)A1, 32);
  int xB0 = __shfl_xor((int)B0, 32);
  int xB1 = __shfl_xor((int)B1, 32);
  const bool hi = quad >= 2;
  const bool odd = quad & 1;
  int Lo0 = hi ? xB0 : (int)A0;   // [A_lo | B_lo]
  int Lo1 = hi ? xB1 : (int)A1;
  int Hi0 = hi ? (int)B0 : xA0;   // [A_hi | B_hi]
  int Hi1 = hi ? (int)B1 : xA1;
  int xLo0 = __shfl_xor(Lo0, 16);
  int xLo1 = __shfl_xor(Lo1, 16);
  int xHi0 = __shfl_xor(Hi0, 16);
  int xHi1 = __shfl_xor(Hi1, 16);
  int4 wv;
  wv.x = odd ? xHi0 : Lo0;   // keys quad*8 + 0,1
  wv.y = odd ? xHi1 : Lo1;   // keys quad*8 + 2,3
  wv.z = odd ? Hi0 : xLo0;   // keys quad*8 + 4,5
  wv.w = odd ? Hi1 : xLo1;   // keys quad*8 + 6,7
  return *(short8*)&wv;
}

// exp + in-register P build + PV for one 16-query half. MASKED compile-time.
template<bool MASKED>
__device__ __forceinline__ void attn_half(
    const f32x4 (&c)[4], float& l_acc, f32x4 (&acc)[4],
    const short8 (&vf0)[4], const short8 (&vf1)[4],
    int keybase, int qabs, int quad)
{
  unsigned pk[4][2];
#pragma unroll
  for (int ct = 0; ct < 4; ++ct) {
    float pe[4];
#pragma unroll
    for (int r = 0; r < 4; ++r) {
      float p = __builtin_amdgcn_exp2f(c[ct][r] * SCL2E);
      if (MASKED && (keybase + ct * 16 + quad * 4 + r > qabs)) p = 0.f;
      pe[r] = p;
      l_acc += p;
    }
    pk[ct][0] = cvtpk_bf16(pe[0], pe[1]);
    pk[ct][1] = cvtpk_bf16(pe[2], pe[3]);
  }
  short8 pa0 = build_pa(pk[0][0], pk[0][1], pk[1][0], pk[1][1], quad);
  short8 pa1 = build_pa(pk[2][0], pk[2][1], pk[3][0], pk[3][1], quad);
  __builtin_amdgcn_s_setprio(1);
#pragma unroll
  for (int nt = 0; nt < 4; ++nt) {
    acc[nt] = __builtin_amdgcn_mfma_f32_16x16x32_bf16(pa0, vf0[nt], acc[nt], 0, 0, 0);
    acc[nt] = __builtin_amdgcn_mfma_f32_16x16x32_bf16(pa1, vf1[nt], acc[nt], 0, 0, 0);
  }
  __builtin_amdgcn_s_setprio(0);
}

// ---------------------------------------------------------------------------
// Flash causal attention v8: 32 queries/block, EIGHT-wave key-split
// (512 threads). Serial depth <= 4 iters/wave; 8192 waves total -> up to
// 32 waves/CU resident (vs r1's 8). Plain launch_bounds(512): compiler
// picks VGPR freely (r2/r3 proved forced caps spill; r1 body alloc'd 72).
// Model: ~4.5K-cycle chain per iteration needs ~6 waves/SIMD to hide;
// r1 had 2 (22% pipe util), this gives 5-7.
// ---------------------------------------------------------------------------
__global__ __launch_bounds__(512) void attn_kernel(
    const ushort* __restrict__ qg, const ushort* __restrict__ kg,
    const ushort* __restrict__ vt, float* __restrict__ out)
{
  __shared__ __align__(16) float accW[4][32][68];   // 34816 B
  __shared__ float lW[8][32];

  const int t = threadIdx.x, bid = blockIdx.x;
  const int batch = (bid & 7) * 2 + ((bid >> 3) & 1);  // 2 batches per XCD
  const int qt = 63 - (bid >> 4);                      // heavy blocks first
  const int q0 = qt * 32;
  const int lane = t & 63, w = t >> 6;                 // w in 0..7
  const int l15 = lane & 15, quad = lane >> 4;
  const size_t bbase = (size_t)batch * SS * DD;

  // Q fragments (B operand of swapped QK): lane l15 = query row
  const ushort* qp = qg + bbase + (size_t)(q0 + l15) * 64 + quad * 8;
  short8 a0 = *(const short8*)qp;
  short8 a1 = *(const short8*)(qp + 32);
  short8 a2 = *(const short8*)(qp + 16 * 64);
  short8 a3 = *(const short8*)(qp + 16 * 64 + 32);

  f32x4 acc0[4], acc1[4];
  float l0 = 0.f, l1 = 0.f;
#pragma unroll
  for (int nt = 0; nt < 4; ++nt) {
    acc0[nt] = (f32x4){0.f, 0.f, 0.f, 0.f};
    acc1[nt] = (f32x4){0.f, 0.f, 0.f, 0.f};
  }

  const int ktotal = ((q0 + 31) >> 6) + 1;   // 64-key tiles (<= 32)
  // wave w starts at tile w; stride 8 tiles = 32768 elems
  const ushort* kp0 = kg + bbase + (size_t)(w * 64 + l15) * 64 + quad * 8;
  const ushort* kp1 = kp0 + 2048;            // +32 key rows
  // vtile[b][kt][d][64]: d = ct*16 + l15, keys quad*8 (+32)
  const ushort* vp = vt + bbase + w * 4096 + l15 * 64 + quad * 8;

  const int qabs0 = q0 + l15, qabs1 = q0 + 16 + l15;

  for (int kt = w; kt < ktotal; kt += 8) {
    short8 kf0[4], kf1[4], vf0[4], vf1[4];
    kf0[0] = *(const short8*)(kp0);
    kf1[0] = *(const short8*)(kp0 + 32);
    kf0[1] = *(const short8*)(kp0 + 1024);
    kf1[1] = *(const short8*)(kp0 + 1056);
    kf0[2] = *(const short8*)(kp1);
    kf1[2] = *(const short8*)(kp1 + 32);
    kf0[3] = *(const short8*)(kp1 + 1024);
    kf1[3] = *(const short8*)(kp1 + 1056);
    vf0[0] = *(const short8*)(vp);         vf1[0] = *(const short8*)(vp + 32);
    vf0[1] = *(const short8*)(vp + 1024);  vf1[1] = *(const short8*)(vp + 1056);
    vf0[2] = *(const short8*)(vp + 2048);  vf1[2] = *(const short8*)(vp + 2080);
    vf0[3] = *(const short8*)(vp + 3072);  vf1[3] = *(const short8*)(vp + 3104);

    // Swapped QK: c = mfma(K, Q) -> S^T tile; lane l15 = query.
    f32x4 c0[4], c1[4];
    __builtin_amdgcn_s_setprio(1);
#pragma unroll
    for (int ct = 0; ct < 4; ++ct) {
      f32x4 z = {0.f, 0.f, 0.f, 0.f};
      c0[ct] = __builtin_amdgcn_mfma_f32_16x16x32_bf16(kf0[ct], a0, z, 0, 0, 0);
      c0[ct] = __builtin_amdgcn_mfma_f32_16x16x32_bf16(kf1[ct], a1, c0[ct], 0, 0, 0);
      c1[ct] = __builtin_amdgcn_mfma_f32_16x16x32_bf16(kf0[ct], a2, z, 0, 0, 0);
      c1[ct] = __builtin_amdgcn_mfma_f32_16x16x32_bf16(kf1[ct], a3, c1[ct], 0, 0, 0);
    }
    __builtin_amdgcn_s_setprio(0);

    const int kb = kt * 64;
    if (kt == ktotal - 1) {
      attn_half<true >(c0, l0, acc0, vf0, vf1, kb, qabs0, quad);
      attn_half<true >(c1, l1, acc1, vf0, vf1, kb, qabs1, quad);
    } else {
      attn_half<false>(c0, l0, acc0, vf0, vf1, kb, qabs0, quad);
      attn_half<false>(c1, l1, acc1, vf0, vf1, kb, qabs1, quad);
    }
    kp0 += 32768; kp1 += 32768; vp += 32768;
  }

  // l per-lane (q = l15); sum across the 4 quads holding different keys
  l0 += __shfl_xor(l0, 16); l0 += __shfl_xor(l0, 32);
  l1 += __shfl_xor(l1, 16); l1 += __shfl_xor(l1, 32);

  if (lane < 16) {
    lW[w][lane] = l0;
    lW[w][16 + lane] = l1;
  }
  // two-stage combine: waves 0-3 write accW[w], waves 4-7 add into accW[w-4]
  if (w < 4) {
#pragma unroll
    for (int r = 0; r < 4; ++r)
#pragma unroll
      for (int nt = 0; nt < 4; ++nt) {
        accW[w][quad * 4 + r][nt * 16 + l15] = acc0[nt][r];
        accW[w][16 + quad * 4 + r][nt * 16 + l15] = acc1[nt][r];
      }
  }
  __syncthreads();
  if (w >= 4) {
#pragma unroll
    for (int r = 0; r < 4; ++r)
#pragma unroll
      for (int nt = 0; nt < 4; ++nt) {
        accW[w - 4][quad * 4 + r][nt * 16 + l15] += acc0[nt][r];
        accW[w - 4][16 + quad * 4 + r][nt * 16 + l15] += acc1[nt][r];
      }
  }
  __syncthreads();

  // final: 512 threads cover 32 rows x 64 cols, 4 floats each
  {
    const int row = t >> 4, col0 = (t & 15) * 4;
    float den = lW[0][row] + lW[1][row] + lW[2][row] + lW[3][row] +
                lW[4][row] + lW[5][row] + lW[6][row] + lW[7][row];
    float iv = 1.0f / den;
    float4 o = {0.f, 0.f, 0.f, 0.f};
#pragma unroll
    for (int ww = 0; ww < 4; ++ww) {
      float4 x0 = *(const float4*)&accW[ww][row][col0];
      o.x += x0.x; o.y += x0.y; o.z += x0.z; o.w += x0.w;
    }
    o.x *= iv; o.y *= iv; o.z *= iv; o.w *= iv;
    *(float4*)(out + bbase + (size_t)(q0 + row) * 64 + col0) = o;
  }
}

extern "C" void kernel_launch(void* const* d_in, const int* in_sizes, int n_in,
                              void* d_out, int out_size, void* d_ws, size_t ws_size,
                              hipStream_t stream) {
  (void)in_sizes; (void)n_in; (void)out_size; (void)ws_size;
  const float* x  = (const float*)d_in[0];
  const float* Wq = (const float*)d_in[1];
  const float* bq = (const float*)d_in[2];
  const float* Wk = (const float*)d_in[3];
  const float* bk = (const float*)d_in[4];
  const float* Wv = (const float*)d_in[5];
  const float* bv = (const float*)d_in[6];
  float* out = (float*)d_out;

  ushort* qws = (ushort*)d_ws;                       // bf16 q: 4 MB
  ushort* kws = qws + (size_t)NB * SS * DD;          // bf16 k: 4 MB
  ushort* vws = kws + (size_t)NB * SS * DD;          // bf16 vtile: 4 MB
  ushort* wt  = vws + (size_t)NB * SS * DD;          // bf16 W^T[3][64][64]: 24 KB

  wprep_kernel<<<dim3(3), dim3(256), 0, stream>>>(Wq, Wk, Wv, wt);
  proj_kernel<<<dim3(512, 3), dim3(256), 0, stream>>>(
      x, wt, bq, bk, bv, qws, kws, vws);
  attn_kernel<<<dim3(NB * (SS / 32)), dim3(512), 0, stream>>>(
      qws, kws, vws, out);
}

// Round 7
// 106.342 us; speedup vs baseline: 1.5733x; 1.2256x over previous
//
#include <hip/hip_runtime.h>

#define NB 16
#define SS 2048
#define DD 64

typedef __attribute__((ext_vector_type(8))) short short8;
typedef __attribute__((ext_vector_type(4))) float f32x4;

// SCALE * log2(e), folded so softmax exp is one v_mul + one v_exp
#define SCL2E 0.18033688011112042f

// async global->LDS, 16B per lane (LDS dest = wave-uniform base + lane*16)
#define GLOAD_LDS(g, l) __builtin_amdgcn_global_load_lds( \
    (const __attribute__((address_space(1))) void*)(g),   \
    (__attribute__((address_space(3))) void*)(l), 16, 0, 0)

// round-to-nearest-even f32 -> bf16 (as raw short)
__device__ __forceinline__ short f2bf(float f) {
  union { float f; unsigned u; } v; v.f = f;
  unsigned r = (v.u + 0x7fffu + ((v.u >> 16) & 1u)) >> 16;
  return (short)r;
}

// packed RNE f32x2 -> bf16x2 (no builtin on gfx950; guide T12)
__device__ __forceinline__ unsigned cvtpk_bf16(float lo, float hi) {
  unsigned r;
  asm("v_cvt_pk_bf16_f32 %0, %1, %2" : "=v"(r) : "v"(lo), "v"(hi));
  return r;
}

__device__ __forceinline__ short8 load_a_frag_f32(const float* p) {
  float4 u = *(const float4*)p;
  float4 w = *(const float4*)(p + 4);
  short8 r;
  r[0] = f2bf(u.x); r[1] = f2bf(u.y); r[2] = f2bf(u.z); r[3] = f2bf(u.w);
  r[4] = f2bf(w.x); r[5] = f2bf(w.y); r[6] = f2bf(w.z); r[7] = f2bf(w.w);
  return r;
}

// ---------------------------------------------------------------------------
// QKV projection (r5 structure, ~33us proven) + PRE-SWIZZLED K and V-tile
// stores: byte_col ^= (row&7)<<4 within each 128B row, so the attn kernel's
// linear global_load_lds staging lands XOR-swizzled content in LDS (rule #21:
// linear dest + pre-swizzled source + swizzled read). Q unswizzled.
// ---------------------------------------------------------------------------
__global__ __launch_bounds__(768) void proj_kernel(
    const float* __restrict__ x,
    const float* __restrict__ Wq, const float* __restrict__ bq,
    const float* __restrict__ Wk, const float* __restrict__ bk,
    const float* __restrict__ Wv, const float* __restrict__ bv,
    ushort* __restrict__ qo, ushort* __restrict__ ko, ushort* __restrict__ vt)
{
  __shared__ __align__(16) ushort Wt[3][64][72];   // W^T[n][k], bf16
  __shared__ __align__(16) ushort Vs[64][68];
  const int t = threadIdx.x;
  // stage all three W^T: 12288 elems over 768 threads
#pragma unroll
  for (int i = 0; i < 4; ++i) {
    int idx = i * 3072 + t * 4;
    int m = idx >> 12, rem = idx & 4095;
    int kk = rem >> 6, n0 = rem & 63;
    const float* src = (m == 0 ? Wq : (m == 1 ? Wk : Wv));
    float4 w4 = *(const float4*)(src + rem);
    Wt[m][n0 + 0][kk] = (ushort)f2bf(w4.x);
    Wt[m][n0 + 1][kk] = (ushort)f2bf(w4.y);
    Wt[m][n0 + 2][kk] = (ushort)f2bf(w4.z);
    Wt[m][n0 + 3][kk] = (ushort)f2bf(w4.w);
  }
  __syncthreads();

  const int lane = t & 63, w = t >> 6;   // w in 0..11
  const int l15 = lane & 15, quad = lane >> 4;
  const int mm = w >> 2, rr = w & 3;     // matrix, row-quarter
  const int g = blockIdx.x * 64 + rr * 16 + l15;

  short8 b0 = load_a_frag_f32(x + (size_t)g * 64 + quad * 8);
  short8 b1 = load_a_frag_f32(x + (size_t)g * 64 + 32 + quad * 8);

  const float* bp = (mm == 0 ? bq : (mm == 1 ? bk : bv));
  ushort* outp = (mm == 0 ? qo : ko);

#pragma unroll
  for (int nt = 0; nt < 4; ++nt) {
    const ushort* ap = &Wt[mm][nt * 16 + l15][quad * 8];
    short8 a0 = *(const short8*)ap;
    short8 a1 = *(const short8*)(ap + 32);
    f32x4 acc = {0.f, 0.f, 0.f, 0.f};
    acc = __builtin_amdgcn_mfma_f32_16x16x32_bf16(a0, b0, acc, 0, 0, 0);
    acc = __builtin_amdgcn_mfma_f32_16x16x32_bf16(a1, b1, acc, 0, 0, 0);
    float4 bb = *(const float4*)(bp + nt * 16 + quad * 4);
    uint2 pk;
    pk.x = cvtpk_bf16(acc[0] + bb.x, acc[1] + bb.y);
    pk.y = cvtpk_bf16(acc[2] + bb.z, acc[3] + bb.w);
    if (mm == 2) {
      *(uint2*)&Vs[rr * 16 + l15][nt * 16 + quad * 4] = pk;
    } else {
      int colb = (nt * 16 + quad * 4) * 2;          // 8B-aligned byte col
      if (mm == 1) colb ^= (g & 7) << 4;            // K: swizzle within row
      *(uint2*)((char*)outp + (size_t)g * 128 + colb) = pk;
    }
  }
  __syncthreads();
  if (t < 256) {
    const int batch = blockIdx.x >> 5;
    const int ktile = blockIdx.x & 31;
    const int d = t >> 2, j0 = (t & 3) * 16;
    ushort tmp[16];
#pragma unroll
    for (int j = 0; j < 16; ++j) tmp[j] = Vs[j0 + j][d];
    // vtile[b][ktile][d][64 keys], swizzled by d-row
    char* base = (char*)vt + ((size_t)batch * SS * DD + ktile * 4096) * 2 + d * 128;
    const int sw = (d & 7) << 4;
    *(int4*)(base + ((j0 * 2) ^ sw)) = ((int4*)tmp)[0];        // keys j0..j0+7
    *(int4*)(base + ((j0 * 2 + 16) ^ sw)) = ((int4*)tmp)[1];   // keys j0+8..+15
  }
}

// ---------------------------------------------------------------------------
// In-register P redistribution (harness-verified r1-r6). One call covers a
// 32-key half: pk[0]=keys 0..15, pk[1]=keys 16..31 (relative to keybase);
// result pa[j] = P[keybase + quad*8 + j].
// ---------------------------------------------------------------------------
__device__ __forceinline__ short8 build_pa(unsigned A0, unsigned A1,
                                           unsigned B0, unsigned B1, int quad) {
  int xA0 = __shfl_xor((int)A0, 32);
  int xA1 = __shfl_xor((int)A1, 32);
  int xB0 = __shfl_xor((int)B0, 32);
  int xB1 = __shfl_xor((int)B1, 32);
  const bool hi = quad >= 2;
  const bool odd = quad & 1;
  int Lo0 = hi ? xB0 : (int)A0;   // [A_lo | B_lo]
  int Lo1 = hi ? xB1 : (int)A1;
  int Hi0 = hi ? (int)B0 : xA0;   // [A_hi | B_hi]
  int Hi1 = hi ? (int)B1 : xA1;
  int xLo0 = __shfl_xor(Lo0, 16);
  int xLo1 = __shfl_xor(Lo1, 16);
  int xHi0 = __shfl_xor(Hi0, 16);
  int xHi1 = __shfl_xor(Hi1, 16);
  int4 wv;
  wv.x = odd ? xHi0 : Lo0;   // keys quad*8 + 0,1
  wv.y = odd ? xHi1 : Lo1;   // keys quad*8 + 2,3
  wv.z = odd ? Hi0 : xLo0;   // keys quad*8 + 4,5
  wv.w = odd ? Hi1 : xLo1;   // keys quad*8 + 6,7
  return *(short8*)&wv;
}

// exp + in-register P build + PV for 16 queries x 32 keys (one key-half).
template<bool MASKED>
__device__ __forceinline__ void attn32(
    const f32x4 (&c)[2], float& l_acc, f32x4 (&acc)[4],
    const short8 (&vf)[4], int keybase, int qabs, int quad)
{
  unsigned pk[2][2];
#pragma unroll
  for (int c2 = 0; c2 < 2; ++c2) {
    float pe[4];
#pragma unroll
    for (int r = 0; r < 4; ++r) {
      float p = __builtin_amdgcn_exp2f(c[c2][r] * SCL2E);
      if (MASKED && (keybase + c2 * 16 + quad * 4 + r > qabs)) p = 0.f;
      pe[r] = p;
      l_acc += p;
    }
    pk[c2][0] = cvtpk_bf16(pe[0], pe[1]);
    pk[c2][1] = cvtpk_bf16(pe[2], pe[3]);
  }
  short8 pa = build_pa(pk[0][0], pk[0][1], pk[1][0], pk[1][1], quad);
  __builtin_amdgcn_s_setprio(1);
#pragma unroll
  for (int nt = 0; nt < 4; ++nt)
    acc[nt] = __builtin_amdgcn_mfma_f32_16x16x32_bf16(pa, vf[nt], acc[nt], 0, 0, 0);
  __builtin_amdgcn_s_setprio(0);
}

// cooperative stage of one 16KB K+V tile: 8 waves x 2KB, 2 gload_lds each
__device__ __forceinline__ void stage_tile(
    char* lds, const ushort* kg, const ushort* vt,
    size_t bbyte, int kt, int seg, int lane)
{
  const char* src = (seg < 4)
      ? (const char*)kg + bbyte + (size_t)kt * 8192 + seg * 2048
      : (const char*)vt + bbyte + (size_t)kt * 8192 + (seg - 4) * 2048;
  char* dst = lds + seg * 2048;   // K at 0..8191, V at 8192..16383 (seg*2048)
  GLOAD_LDS(src + lane * 16, dst);
  GLOAD_LDS(src + 1024 + lane * 16, dst + 1024);
}

// ---------------------------------------------------------------------------
// Flash causal attention v9: LDS-staged double-buffered K/V (T3 minimum
// 2-phase: STAGE(next) -> compute(cur) -> syncthreads [= vmcnt(0)+barrier]).
// 64 queries/block, 8 waves = 4 q-subtiles x 2 key-halves. Per-iter loads are
// ~120cy LDS reads instead of ~400cy L2 round trips; global latency hides
// under the whole block's tile compute. XOR-swizzled tiles: conflict-free
// ds_read_b128 (content pre-swizzled by proj, staged linearly).
// ---------------------------------------------------------------------------
__global__ __launch_bounds__(512) void attn_kernel(
    const ushort* __restrict__ qg, const ushort* __restrict__ kg,
    const ushort* __restrict__ vt, float* __restrict__ out)
{
  __shared__ __align__(16) char KV[2][16384];   // per buf: K 8KB | V 8KB

  const int t = threadIdx.x, bid = blockIdx.x;
  const int batch = (bid & 7) * 2 + ((bid >> 3) & 1);  // 2 batches per XCD
  const int qt = 31 - (bid >> 4);                      // 64q tile, heavy first
  const int lane = t & 63, w = t >> 6;                 // 8 waves
  const int l15 = lane & 15, quad = lane >> 4;
  const int h = w >> 2;                                // key half (0/1)
  const int qgi = w & 3;                               // query subtile
  const int qrow0 = qt * 64 + qgi * 16;
  const size_t bbase = (size_t)batch * SS * DD;        // elements
  const size_t bbyte = bbase * 2;                      // bytes

  // Q fragments (B operand of swapped QK): lane l15 = query row
  const ushort* qp = qg + bbase + (size_t)(qrow0 + l15) * 64 + quad * 8;
  short8 a0 = *(const short8*)qp;
  short8 a1 = *(const short8*)(qp + 32);

  f32x4 acc[4];
  float l = 0.f;
#pragma unroll
  for (int nt = 0; nt < 4; ++nt) acc[nt] = (f32x4){0.f, 0.f, 0.f, 0.f};

  const int ktotal = qt + 1;
  const int qabs = qrow0 + l15;

  stage_tile(&KV[0][0], kg, vt, bbyte, 0, w, lane);
  __syncthreads();   // drains vmcnt(0): buf0 ready

  int cur = 0;
  for (int kt = 0; kt < ktotal; ++kt) {
    if (kt + 1 < ktotal)
      stage_tile(&KV[cur ^ 1][0], kg, vt, bbyte, kt + 1, w, lane);

    const char* Kb = &KV[cur][0];
    const char* Vb = &KV[cur][8192];
    short8 kf0[2], kf1[2], vf[4];
#pragma unroll
    for (int c2 = 0; c2 < 2; ++c2) {
      int row = (2 * h + c2) * 16 + l15;      // key row in tile
      int sw = (row & 7) << 4;
      kf0[c2] = *(const short8*)(Kb + row * 128 + ((quad * 16) ^ sw));
      kf1[c2] = *(const short8*)(Kb + row * 128 + ((64 + quad * 16) ^ sw));
    }
#pragma unroll
    for (int nt = 0; nt < 4; ++nt) {
      int drow = nt * 16 + l15;               // d row in V tile
      int sv = (drow & 7) << 4;
      vf[nt] = *(const short8*)(Vb + drow * 128 + ((h * 64 + quad * 16) ^ sv));
    }

    // Swapped QK: c = mfma(K, Q) -> S^T; lane l15 = query.
    f32x4 c[2];
    __builtin_amdgcn_s_setprio(1);
#pragma unroll
    for (int c2 = 0; c2 < 2; ++c2) {
      f32x4 z = {0.f, 0.f, 0.f, 0.f};
      c[c2] = __builtin_amdgcn_mfma_f32_16x16x32_bf16(kf0[c2], a0, z, 0, 0, 0);
      c[c2] = __builtin_amdgcn_mfma_f32_16x16x32_bf16(kf1[c2], a1, c[c2], 0, 0, 0);
    }
    __builtin_amdgcn_s_setprio(0);

    const int keybase = kt * 64 + h * 32;
    if (kt == ktotal - 1)
      attn32<true >(c, l, acc, vf, keybase, qabs, quad);
    else
      attn32<false>(c, l, acc, vf, keybase, qabs, quad);

    __syncthreads();   // vmcnt(0) drain of stage + barrier (T3-min)
    cur ^= 1;
  }

  // l per-lane (q = l15); fold the 4 quads (each held different keys)
  l += __shfl_xor(l, 16);
  l += __shfl_xor(l, 32);

  // 2-way combine of key-halves through the (now free) staging LDS
  float* S = (float*)&KV[qgi >> 1][(qgi & 1) * 8192];
  if (h == 1) {
#pragma unroll
    for (int r = 0; r < 4; ++r)
#pragma unroll
      for (int nt = 0; nt < 4; ++nt)
        S[(quad * 4 + r) * 68 + nt * 16 + l15] = acc[nt][r];
    if (lane < 16) S[1088 + lane] = l;
  }
  __syncthreads();
  if (h == 0) {
    float lt = l + S[1088 + l15];   // total denom for q = l15
#pragma unroll
    for (int r = 0; r < 4; ++r) {
      float iv = 1.0f / __shfl(lt, quad * 4 + r);
      float* orow = out + bbase + (size_t)(qrow0 + quad * 4 + r) * 64 + l15;
#pragma unroll
      for (int nt = 0; nt < 4; ++nt)
        orow[nt * 16] = (acc[nt][r] + S[(quad * 4 + r) * 68 + nt * 16 + l15]) * iv;
    }
  }
}

extern "C" void kernel_launch(void* const* d_in, const int* in_sizes, int n_in,
                              void* d_out, int out_size, void* d_ws, size_t ws_size,
                              hipStream_t stream) {
  (void)in_sizes; (void)n_in; (void)out_size; (void)ws_size;
  const float* x  = (const float*)d_in[0];
  const float* Wq = (const float*)d_in[1];
  const float* bq = (const float*)d_in[2];
  const float* Wk = (const float*)d_in[3];
  const float* bk = (const float*)d_in[4];
  const float* Wv = (const float*)d_in[5];
  const float* bv = (const float*)d_in[6];
  float* out = (float*)d_out;

  ushort* qws = (ushort*)d_ws;                       // bf16 q: 4 MB
  ushort* kws = qws + (size_t)NB * SS * DD;          // bf16 k (swizzled): 4 MB
  ushort* vws = kws + (size_t)NB * SS * DD;          // bf16 vtile (swizzled): 4 MB

  proj_kernel<<<dim3(NB * SS / 64), dim3(768), 0, stream>>>(
      x, Wq, bq, Wk, bk, Wv, bv, qws, kws, vws);
  attn_kernel<<<dim3(NB * (SS / 64)), dim3(512), 0, stream>>>(
      qws, kws, vws, out);
}